// Round 17
// baseline (434.807 us; speedup 1.0000x reference)
//
#include <hip/hip_runtime.h>
#include <hip/hip_bf16.h>

typedef __bf16 bf16x8 __attribute__((ext_vector_type(8)));
typedef __bf16 bf16x4 __attribute__((ext_vector_type(4)));
typedef __bf16 bf16x2 __attribute__((ext_vector_type(2)));
typedef float  f32x4  __attribute__((ext_vector_type(4)));

#define T_LEN 4096
#define QBLK  128
#define NIT   32          // 32 superblocks x 128 s

__device__ __forceinline__ int swz(int row, int colByte) {
    return row * 128 + (colByte ^ (((row ^ (row >> 2)) & 7) << 4));
}
__device__ __forceinline__ int swzM(int row, int colByte) {   // merge buf [c][t] f32
    return row * 128 + (colByte ^ ((row & 7) << 4));
}
__device__ __forceinline__ int swzO(int row, int colByte) {   // epilogue f32 [c][128t]
    return row * 512 + (colByte ^ ((row & 7) << 5));
}

// Q pre-scale: 1/8 (QK scale) x log2(e); no-max exp2 softmax (r9-verified).
#define QSCALE 0.18033688011112042f

#if __has_builtin(__builtin_amdgcn_exp2f)
#define EXP2(x) __builtin_amdgcn_exp2f(x)
#else
__device__ __forceinline__ float EXP2(float x) {
    float r; asm("v_exp_f32 %0, %1" : "=v"(r) : "v"(x)); return r;
}
#endif

__device__ __forceinline__ void glds16(const void* g, void* l) {
    __builtin_amdgcn_global_load_lds(
        (const __attribute__((address_space(1))) void*)g,
        (__attribute__((address_space(3))) void*)l, 16, 0, 0);
}

// ---------------- prepass: K,V -> bf16 swizzled LDS images in d_ws ----------
__global__ __launch_bounds__(256)
void qkv_prepass(const float* __restrict__ qkv, char* __restrict__ kpan,
                 char* __restrict__ vpan) {
    const int tile = blockIdx.x;    // 0..63
    const int bh   = blockIdx.y;    // 0..15
    const float* kp = qkv + ((size_t)bh * 192 + 64)  * T_LEN + tile * 64;
    const float* vp = qkv + ((size_t)bh * 192 + 128) * T_LEN + tile * 64;
    char* kout = kpan + (size_t)(bh * 64 + tile) * 8192;
    char* vout = vpan + (size_t)(bh * 64 + tile) * 8192;

    const int t  = threadIdx.x;
    const int s  = t & 63;
    const int o4 = t >> 6;          // 0..3
    #pragma unroll
    for (int oo = 0; oo < 2; ++oo) {
        const int oct = o4 + oo * 4;                 // c-octet 0..7
        bf16x8 v;
        #pragma unroll
        for (int j = 0; j < 8; ++j)
            v[j] = (__bf16)kp[(size_t)(oct * 8 + j) * T_LEN + s];
        *(bf16x8*)(kout + swz(s, oct * 16)) = v;
    }
    const int c = t & 63;
    #pragma unroll
    for (int p = 0; p < 4; ++p) {
        const int u = o4 * 4 + p;                    // s-chunk 0..15
        float4 f = *(const float4*)(vp + (size_t)c * T_LEN + u * 4);
        const int up = (u & 8) | ((u & 3) << 1) | ((u >> 2) & 1);
        bf16x4 hv;
        hv[0] = (__bf16)f.x; hv[1] = (__bf16)f.y;
        hv[2] = (__bf16)f.z; hv[3] = (__bf16)f.w;
        *(bf16x4*)(vout + swz(c, up * 8)) = hv;
    }
}

// ---------------- main: 16 waves = 4 t-groups x 4 s-quarters ----------------
// Per-CU LDS-read volume identical to r16 (reuse R=2 kept), but 32 waves/CU
// (8/SIMD, the HW cap) instead of 16 -> doubles latency hiding in a regime
// where no pipe exceeds ~50% (r16 counters). Additive no-max softmax makes
// the 4-way s-merge a cheap post-loop tree.
// LDS map: [0,16K) Qs (dead after qreg; lA/lB + Obuf reuse) |
//          [16K,48K) Ks dbuf 2x16K | [48K,80K) Vs dbuf 2x16K.
// Post-loop: merge regions reuse [16K,80K); Obuf reuses [0,32K).
__global__ __launch_bounds__(1024, 8)
void qkv_attn_glds(const float* __restrict__ qkv, float* __restrict__ out,
                   const char* __restrict__ kpan, const char* __restrict__ vpan) {
    __shared__ __align__(16) char lds[81920];

    const int fid   = (blockIdx.x & 7) * 64 + (blockIdx.x >> 3);   // T1 swizzle
    const int bh    = fid >> 5;
    const int ttile = fid & 31;
    const float* qp = qkv + (size_t)bh * 192 * T_LEN;
    const char* kpb = kpan + (size_t)bh * 64 * 8192;
    const char* vpb = vpan + (size_t)bh * 64 * 8192;
    const int t0 = ttile * QBLK;

    const int tid  = threadIdx.x;           // 0..1023
    const int wave = tid >> 6, lane = tid & 63;
    const int g = lane >> 4, i = lane & 15;
    const int tg = wave >> 2;               // t-group: 32 rows
    const int sh = wave & 3;                // s-quarter of the 128-s superblock
    const int ta = sh >> 1, hf = sh & 1;    // tile-within-superblock, 32s half

    // ---- prologue: async-stage superblock 0 (tiles 0,1) ----
    glds16(kpb + tid * 16, lds + 16384 + wave * 1024);
    glds16(vpb + tid * 16, lds + 49152 + wave * 1024);

    // ---- stage Q^T x QSCALE : [128 t][64 c] (1024 thr: 1 cpair x 4t each) ----
    {
        const int tq    = (tid & 31) * 4;   // 0..124
        const int cpair = tid >> 5;         // 0..31
        const float* base = qp + (size_t)(cpair * 2) * T_LEN + t0 + tq;
        float4 lo = *(const float4*)(base);
        float4 hi = *(const float4*)(base + T_LEN);
        bf16x2 v;
        v[0] = (__bf16)(lo.x * QSCALE); v[1] = (__bf16)(hi.x * QSCALE);
        *(bf16x2*)(lds + swz(tq + 0, cpair * 4)) = v;
        v[0] = (__bf16)(lo.y * QSCALE); v[1] = (__bf16)(hi.y * QSCALE);
        *(bf16x2*)(lds + swz(tq + 1, cpair * 4)) = v;
        v[0] = (__bf16)(lo.z * QSCALE); v[1] = (__bf16)(hi.z * QSCALE);
        *(bf16x2*)(lds + swz(tq + 2, cpair * 4)) = v;
        v[0] = (__bf16)(lo.w * QSCALE); v[1] = (__bf16)(hi.w * QSCALE);
        *(bf16x2*)(lds + swz(tq + 3, cpair * 4)) = v;
    }
    __syncthreads();   // Q staged + superblock 0 drained
    bf16x8 qreg[2][2];   // [t-half][kk], loop-invariant; Qs LDS dead after
    #pragma unroll
    for (int h = 0; h < 2; ++h)
        #pragma unroll
        for (int kk = 0; kk < 2; ++kk)
            qreg[h][kk] = *(const bf16x8*)(lds + swz(tg * 32 + h * 16 + i, kk * 64 + g * 16));

    f32x4 oacc[2][4];
    #pragma unroll
    for (int h = 0; h < 2; ++h)
        #pragma unroll
        for (int n = 0; n < 4; ++n) oacc[h][n] = (f32x4){0.f, 0.f, 0.f, 0.f};
    float l0 = 0.f, l1 = 0.f;   // lane-local partials (my 32s); reduced post-loop

    for (int it = 0; it < NIT; ++it) {
        if (it + 1 < NIT) {     // async-issue next superblock
            const size_t off = (size_t)(2 * it + 2) * 8192;
            const int b = (it + 1) & 1;
            glds16(kpb + off + tid * 16, lds + 16384 + b * 16384 + wave * 1024);
            glds16(vpb + off + tid * 16, lds + 49152 + b * 16384 + wave * 1024);
        }
        // ---- single 32t x 32s chain (my quarter) ----
        char* KsR = lds + 16384 + (it & 1) * 16384 + ta * 8192;
        char* VsR = lds + 49152 + (it & 1) * 16384 + ta * 8192;
        f32x4 sacc[2][2];
        #pragma unroll
        for (int h = 0; h < 2; ++h)
            #pragma unroll
            for (int mt = 0; mt < 2; ++mt) sacc[h][mt] = (f32x4){0.f, 0.f, 0.f, 0.f};
        #pragma unroll
        for (int kk = 0; kk < 2; ++kk)
            #pragma unroll
            for (int mt = 0; mt < 2; ++mt) {
                bf16x8 kf = *(const bf16x8*)(KsR + swz(hf * 32 + mt * 16 + i, kk * 64 + g * 16));
                sacc[0][mt] = __builtin_amdgcn_mfma_f32_16x16x32_bf16(kf, qreg[0][kk], sacc[0][mt], 0, 0, 0);
                sacc[1][mt] = __builtin_amdgcn_mfma_f32_16x16x32_bf16(kf, qreg[1][kk], sacc[1][mt], 0, 0, 0);
            }
        bf16x8 pa0, pa1;
        #pragma unroll
        for (int r = 0; r < 4; ++r) {
            float a0 = EXP2(sacc[0][0][r]);
            float a1 = EXP2(sacc[0][1][r]);
            l0 += a0 + a1;
            pa0[r] = (__bf16)a0; pa0[4 + r] = (__bf16)a1;
            float b0 = EXP2(sacc[1][0][r]);
            float b1 = EXP2(sacc[1][1][r]);
            l1 += b0 + b1;
            pa1[r] = (__bf16)b0; pa1[4 + r] = (__bf16)b1;
        }
        #pragma unroll
        for (int n = 0; n < 4; ++n) {
            bf16x8 bv = *(const bf16x8*)(VsR + swz(n * 16 + i, hf * 64 + g * 16));
            oacc[0][n] = __builtin_amdgcn_mfma_f32_16x16x32_bf16(pa0, bv, oacc[0][n], 0, 0, 0);
            oacc[1][n] = __builtin_amdgcn_mfma_f32_16x16x32_bf16(pa1, bv, oacc[1][n], 0, 0, 0);
        }
        __syncthreads();   // next bufs ready (drains glds); reads fenced
    }
    l0 += __shfl_xor(l0, 16); l0 += __shfl_xor(l0, 32);
    l1 += __shfl_xor(l1, 16); l1 += __shfl_xor(l1, 32);

    // ---- 4-way additive s-merge (2-stage tree), then epilogue ----
    // Region (tg*2 + ta) works for writer (hf==1) and its reader (hf==0):
    // sh1 -> sh0 use region tg*2; sh3 -> sh2 use region tg*2+1.
    char* regA = lds + 16384 + (tg * 2 + ta) * 8192;   // [64c][32t] f32, swzM
    float* lA = (float*)lds;                           // [2][128] in dead Qs
    float* lB = (float*)(lds + 1024);
    if (hf == 1) {
        #pragma unroll
        for (int h = 0; h < 2; ++h)
            #pragma unroll
            for (int n = 0; n < 4; ++n)
                *(f32x4*)(regA + swzM(n * 16 + i, h * 64 + g * 16)) = oacc[h][n];
        if (g == 0) { lA[ta * 128 + tg * 32 + i] = l0; lA[ta * 128 + tg * 32 + 16 + i] = l1; }
    }
    __syncthreads();
    if (hf == 0) {
        #pragma unroll
        for (int h = 0; h < 2; ++h)
            #pragma unroll
            for (int n = 0; n < 4; ++n)
                oacc[h][n] += *(const f32x4*)(regA + swzM(n * 16 + i, h * 64 + g * 16));
        l0 += lA[ta * 128 + tg * 32 + i];
        l1 += lA[ta * 128 + tg * 32 + 16 + i];
    }
    __syncthreads();
    char* regB = lds + 16384 + (tg * 2) * 8192;        // even regions reused
    if (sh == 2) {
        #pragma unroll
        for (int h = 0; h < 2; ++h)
            #pragma unroll
            for (int n = 0; n < 4; ++n)
                *(f32x4*)(regB + swzM(n * 16 + i, h * 64 + g * 16)) = oacc[h][n];
        if (g == 0) { lB[tg * 32 + i] = l0; lB[tg * 32 + 16 + i] = l1; }
    }
    __syncthreads();
    if (sh == 0) {
        #pragma unroll
        for (int h = 0; h < 2; ++h)
            #pragma unroll
            for (int n = 0; n < 4; ++n)
                oacc[h][n] += *(const f32x4*)(regB + swzM(n * 16 + i, h * 64 + g * 16));
        l0 += lB[tg * 32 + i];
        l1 += lB[tg * 32 + 16 + i];
    }
    __syncthreads();   // all lA/lB + region reads done before Obuf overwrite
    if (sh == 0) {
        #pragma unroll
        for (int h = 0; h < 2; ++h) {
            float invl = 1.0f / (h ? l1 : l0);
            #pragma unroll
            for (int reg = 0; reg < 4; ++reg) {
                float inv_r = __shfl(invl, g * 4 + reg);
                int t_loc = tg * 32 + h * 16 + g * 4 + reg;
                #pragma unroll
                for (int n = 0; n < 4; ++n) {
                    int c = n * 16 + i;
                    *(float*)(lds + swzO(c, t_loc * 4)) = oacc[h][n][reg] * inv_r;
                }
            }
        }
    }
    __syncthreads();
    #pragma unroll
    for (int it = 0; it < 2; ++it) {
        int idx = it * 1024 + tid;      // 2048 chunks of 16B
        int c   = idx >> 5;
        int seg = idx & 31;
        float4 u = *(const float4*)(lds + swzO(c, seg * 16));
        *(float4*)(out + (size_t)(bh * 64 + c) * T_LEN + t0 + seg * 4) = u;
    }
}

// ---------------- tiny correct fallback (ws too small; r3-verified) ---------
__global__ __launch_bounds__(256)
void simple_attn(const float* __restrict__ qkv, float* __restrict__ out) {
    const int wave = threadIdx.x >> 6;
    const int lane = threadIdx.x & 63;
    const int t  = blockIdx.x * 4 + wave;
    const int bh = blockIdx.y;
    const float* qp = qkv + (size_t)bh * 192 * T_LEN;
    const float* kp = qp + (size_t)64  * T_LEN;
    const float* vp = qp + (size_t)128 * T_LEN;
    const float qc = qp[(size_t)lane * T_LEN + t] * 0.125f;
    float m = -1e30f, l = 0.f, o = 0.f;
    for (int s = 0; s < T_LEN; ++s) {
        float prod = qc * kp[(size_t)lane * T_LEN + s];
        #pragma unroll
        for (int d = 1; d < 64; d <<= 1) prod += __shfl_xor(prod, d);
        const float nm   = fmaxf(m, prod);
        const float corr = __expf(m - nm);
        const float p    = __expf(prod - nm);
        l = l * corr + p;
        o = o * corr + p * vp[(size_t)lane * T_LEN + s];
        m = nm;
    }
    out[(size_t)(bh * 64 + lane) * T_LEN + t] = o / l;
}

extern "C" void kernel_launch(void* const* d_in, const int* in_sizes, int n_in,
                              void* d_out, int out_size, void* d_ws, size_t ws_size,
                              hipStream_t stream) {
    const float* qkv = (const float*)d_in[0];
    float* out = (float*)d_out;
    const size_t pan_bytes = (size_t)16 * 64 * 8192;   // 8.39 MB per panel set
    if (ws_size >= 2 * pan_bytes) {
        char* kpan = (char*)d_ws;
        char* vpan = kpan + pan_bytes;
        qkv_prepass<<<dim3(64, 16), 256, 0, stream>>>(qkv, kpan, vpan);
        qkv_attn_glds<<<dim3(512), 1024, 0, stream>>>(qkv, out, kpan, vpan);
    } else {
        simple_attn<<<dim3(T_LEN / 4, 16), 256, 0, stream>>>(qkv, out);
    }
}

// Round 18
// 89.002 us; speedup vs baseline: 4.8854x; 4.8854x over previous
//
#include <hip/hip_runtime.h>
#include <hip/hip_bf16.h>

typedef __bf16 bf16x8 __attribute__((ext_vector_type(8)));
typedef __bf16 bf16x4 __attribute__((ext_vector_type(4)));
typedef __bf16 bf16x2 __attribute__((ext_vector_type(2)));
typedef float  f32x4  __attribute__((ext_vector_type(4)));

#define T_LEN 4096
#define QBLK  128
#define NIT   32          // 32 superblocks x 128 s

__device__ __forceinline__ int swz(int row, int colByte) {
    return row * 128 + (colByte ^ (((row ^ (row >> 2)) & 7) << 4));
}
__device__ __forceinline__ int swzM(int row, int colByte) {   // merge buf [c][t] f32
    return row * 128 + (colByte ^ ((row & 7) << 4));
}
__device__ __forceinline__ int swzO(int row, int colByte) {   // epilogue f32 [c][128t]
    return row * 512 + (colByte ^ ((row & 7) << 5));
}

// Q pre-scale: 1/8 (QK scale) x log2(e); no-max exp2 softmax (r9-verified).
#define QSCALE 0.18033688011112042f

#if __has_builtin(__builtin_amdgcn_exp2f)
#define EXP2(x) __builtin_amdgcn_exp2f(x)
#else
__device__ __forceinline__ float EXP2(float x) {
    float r; asm("v_exp_f32 %0, %1" : "=v"(r) : "v"(x)); return r;
}
#endif

__device__ __forceinline__ void glds16(const void* g, void* l) {
    __builtin_amdgcn_global_load_lds(
        (const __attribute__((address_space(1))) void*)g,
        (__attribute__((address_space(3))) void*)l, 16, 0, 0);
}

// ---------------- prepass: K,V -> bf16 swizzled LDS images in d_ws ----------
__global__ __launch_bounds__(256)
void qkv_prepass(const float* __restrict__ qkv, char* __restrict__ kpan,
                 char* __restrict__ vpan) {
    const int tile = blockIdx.x;    // 0..63
    const int bh   = blockIdx.y;    // 0..15
    const float* kp = qkv + ((size_t)bh * 192 + 64)  * T_LEN + tile * 64;
    const float* vp = qkv + ((size_t)bh * 192 + 128) * T_LEN + tile * 64;
    char* kout = kpan + (size_t)(bh * 64 + tile) * 8192;
    char* vout = vpan + (size_t)(bh * 64 + tile) * 8192;

    const int t  = threadIdx.x;
    const int s  = t & 63;
    const int o4 = t >> 6;          // 0..3
    #pragma unroll
    for (int oo = 0; oo < 2; ++oo) {
        const int oct = o4 + oo * 4;                 // c-octet 0..7
        bf16x8 v;
        #pragma unroll
        for (int j = 0; j < 8; ++j)
            v[j] = (__bf16)kp[(size_t)(oct * 8 + j) * T_LEN + s];
        *(bf16x8*)(kout + swz(s, oct * 16)) = v;
    }
    const int c = t & 63;
    #pragma unroll
    for (int p = 0; p < 4; ++p) {
        const int u = o4 * 4 + p;                    // s-chunk 0..15
        float4 f = *(const float4*)(vp + (size_t)c * T_LEN + u * 4);
        const int up = (u & 8) | ((u & 3) << 1) | ((u >> 2) & 1);
        bf16x4 hv;
        hv[0] = (__bf16)f.x; hv[1] = (__bf16)f.y;
        hv[2] = (__bf16)f.z; hv[3] = (__bf16)f.w;
        *(bf16x4*)(vout + swz(c, up * 8)) = hv;
    }
}

// ---------------- main: r16 structure + phase-grouping + setprio ------------
// 8 waves = 4 t-groups x 2 s-halves; 2 blocks/CU (4 waves/SIMD — the VGPR
// ceiling per r17's spill lesson: 8 waves/SIMD needs <=64 total regs, infeasible).
// Superblock (2x64s tiles) per barrier; phases grouped: {S: K-reads+16 MFMA}
// {exp: 32 exp2+pack} {PV: V-reads+16 MFMA} — bigger independent pools per
// pipe, setprio(1) (T5) around MFMA clusters.
// LDS map: [0,16K) Qs (dead after qreg; lA + Obuf reuse) |
//          [16K,48K) Ks dbuf 2x16K (mbase reuse post-loop) | [48K,80K) Vs dbuf.
__global__ __launch_bounds__(512, 4)
void qkv_attn_glds(const float* __restrict__ qkv, float* __restrict__ out,
                   const char* __restrict__ kpan, const char* __restrict__ vpan) {
    __shared__ __align__(16) char lds[81920];

    const int fid   = (blockIdx.x & 7) * 64 + (blockIdx.x >> 3);   // T1 swizzle
    const int bh    = fid >> 5;
    const int ttile = fid & 31;
    const float* qp = qkv + (size_t)bh * 192 * T_LEN;
    const char* kpb = kpan + (size_t)bh * 64 * 8192;
    const char* vpb = vpan + (size_t)bh * 64 * 8192;
    const int t0 = ttile * QBLK;

    const int tid  = threadIdx.x;
    const int wave = tid >> 6, lane = tid & 63;
    const int g = lane >> 4, i = lane & 15;
    const int tg = wave >> 1, half = wave & 1;   // t-group (32 rows), s-half

    // ---- prologue: async-stage superblock 0 (tiles 0,1) ----
    glds16(kpb + tid * 16,        lds + 16384 + wave * 1024);
    glds16(kpb + 8192 + tid * 16, lds + 16384 + 8192 + wave * 1024);
    glds16(vpb + tid * 16,        lds + 49152 + wave * 1024);
    glds16(vpb + 8192 + tid * 16, lds + 49152 + 8192 + wave * 1024);

    // ---- stage Q^T x QSCALE : [128 t][64 c] ----
    {
        const int tq  = (tid & 31) * 4;
        const int cp8 = tid >> 5;
        #pragma unroll
        for (int hh = 0; hh < 2; ++hh) {
            const int cpair = cp8 + hh * 16;
            const float* base = qp + (size_t)(cpair * 2) * T_LEN + t0 + tq;
            float4 lo = *(const float4*)(base);
            float4 hi = *(const float4*)(base + T_LEN);
            bf16x2 v;
            v[0] = (__bf16)(lo.x * QSCALE); v[1] = (__bf16)(hi.x * QSCALE);
            *(bf16x2*)(lds + swz(tq + 0, cpair * 4)) = v;
            v[0] = (__bf16)(lo.y * QSCALE); v[1] = (__bf16)(hi.y * QSCALE);
            *(bf16x2*)(lds + swz(tq + 1, cpair * 4)) = v;
            v[0] = (__bf16)(lo.z * QSCALE); v[1] = (__bf16)(hi.z * QSCALE);
            *(bf16x2*)(lds + swz(tq + 2, cpair * 4)) = v;
            v[0] = (__bf16)(lo.w * QSCALE); v[1] = (__bf16)(hi.w * QSCALE);
            *(bf16x2*)(lds + swz(tq + 3, cpair * 4)) = v;
        }
    }
    __syncthreads();   // Q staged + superblock 0 drained
    bf16x8 qreg[2][2];   // [t-half][kk], loop-invariant; Qs LDS dead after
    #pragma unroll
    for (int h = 0; h < 2; ++h)
        #pragma unroll
        for (int kk = 0; kk < 2; ++kk)
            qreg[h][kk] = *(const bf16x8*)(lds + swz(tg * 32 + h * 16 + i, kk * 64 + g * 16));

    f32x4 oacc[2][4];
    #pragma unroll
    for (int h = 0; h < 2; ++h)
        #pragma unroll
        for (int n = 0; n < 4; ++n) oacc[h][n] = (f32x4){0.f, 0.f, 0.f, 0.f};
    float l0 = 0.f, l1 = 0.f;   // lane-local partials; shfl-reduced post-loop

    for (int it = 0; it < NIT; ++it) {
        // ---- async-issue next superblock ----
        if (it + 1 < NIT) {
            const size_t off = (size_t)(2 * it + 2) * 8192;
            const int b = (it + 1) & 1;
            glds16(kpb + off + tid * 16,        lds + 16384 + b * 16384 + wave * 1024);
            glds16(kpb + off + 8192 + tid * 16, lds + 16384 + b * 16384 + 8192 + wave * 1024);
            glds16(vpb + off + tid * 16,        lds + 49152 + b * 16384 + wave * 1024);
            glds16(vpb + off + 8192 + tid * 16, lds + 49152 + b * 16384 + 8192 + wave * 1024);
        }
        char* KsB = lds + 16384 + (it & 1) * 16384;
        char* VsB = lds + 49152 + (it & 1) * 16384;

        // ---- S phase: both chains' K-frags + 32 S-MFMAs ----
        f32x4 sacc[2][2][2];   // [ta][t-half][mt]
        #pragma unroll
        for (int ta = 0; ta < 2; ++ta)
            #pragma unroll
            for (int h = 0; h < 2; ++h)
                #pragma unroll
                for (int mt = 0; mt < 2; ++mt) sacc[ta][h][mt] = (f32x4){0.f, 0.f, 0.f, 0.f};
        __builtin_amdgcn_s_setprio(1);
        #pragma unroll
        for (int ta = 0; ta < 2; ++ta)
            #pragma unroll
            for (int kk = 0; kk < 2; ++kk)
                #pragma unroll
                for (int mt = 0; mt < 2; ++mt) {
                    bf16x8 kf = *(const bf16x8*)(KsB + ta * 8192 + swz(half * 32 + mt * 16 + i, kk * 64 + g * 16));
                    sacc[ta][0][mt] = __builtin_amdgcn_mfma_f32_16x16x32_bf16(kf, qreg[0][kk], sacc[ta][0][mt], 0, 0, 0);
                    sacc[ta][1][mt] = __builtin_amdgcn_mfma_f32_16x16x32_bf16(kf, qreg[1][kk], sacc[ta][1][mt], 0, 0, 0);
                }
        __builtin_amdgcn_s_setprio(0);

        // ---- exp phase: 32 exp2 + packs ----
        bf16x8 pa[2][2];   // [ta][t-half]
        #pragma unroll
        for (int ta = 0; ta < 2; ++ta)
            #pragma unroll
            for (int r = 0; r < 4; ++r) {
                float a0 = EXP2(sacc[ta][0][0][r]);
                float a1 = EXP2(sacc[ta][0][1][r]);
                l0 += a0 + a1;
                pa[ta][0][r] = (__bf16)a0; pa[ta][0][4 + r] = (__bf16)a1;
                float b0 = EXP2(sacc[ta][1][0][r]);
                float b1 = EXP2(sacc[ta][1][1][r]);
                l1 += b0 + b1;
                pa[ta][1][r] = (__bf16)b0; pa[ta][1][4 + r] = (__bf16)b1;
            }

        // ---- PV phase: 8 V-frags + 32 PV-MFMAs ----
        __builtin_amdgcn_s_setprio(1);
        #pragma unroll
        for (int ta = 0; ta < 2; ++ta)
            #pragma unroll
            for (int n = 0; n < 4; ++n) {
                bf16x8 bv = *(const bf16x8*)(VsB + ta * 8192 + swz(n * 16 + i, half * 64 + g * 16));
                oacc[0][n] = __builtin_amdgcn_mfma_f32_16x16x32_bf16(pa[ta][0], bv, oacc[0][n], 0, 0, 0);
                oacc[1][n] = __builtin_amdgcn_mfma_f32_16x16x32_bf16(pa[ta][1], bv, oacc[1][n], 0, 0, 0);
            }
        __builtin_amdgcn_s_setprio(0);
        __syncthreads();   // next bufs ready (drains glds); reads fenced
    }
    l0 += __shfl_xor(l0, 16); l0 += __shfl_xor(l0, 32);
    l1 += __shfl_xor(l1, 16); l1 += __shfl_xor(l1, 32);

    // ---- merge s-halves (additive), then epilogue ----
    char* mbase = lds + 16384 + tg * 8192;   // [64 c][32 t] f32, swzM (K dbuf dead)
    float* lbase = (float*)(lds);            // Qs region dead
    if (half == 1) {
        #pragma unroll
        for (int h = 0; h < 2; ++h)
            #pragma unroll
            for (int n = 0; n < 4; ++n)
                *(f32x4*)(mbase + swzM(n * 16 + i, h * 64 + g * 16)) = oacc[h][n];
        if (g == 0) { lbase[tg * 32 + i] = l0; lbase[tg * 32 + 16 + i] = l1; }
    }
    __syncthreads();
    if (half == 0) {
        #pragma unroll
        for (int h = 0; h < 2; ++h)
            #pragma unroll
            for (int n = 0; n < 4; ++n)
                oacc[h][n] += *(const f32x4*)(mbase + swzM(n * 16 + i, h * 64 + g * 16));
        l0 += lbase[tg * 32 + i];
        l1 += lbase[tg * 32 + 16 + i];
    }
    __syncthreads();   // merge reads done before Obuf overwrites [0,32K)
    if (half == 0) {
        #pragma unroll
        for (int h = 0; h < 2; ++h) {
            float invl = 1.0f / (h ? l1 : l0);
            #pragma unroll
            for (int reg = 0; reg < 4; ++reg) {
                float inv_r = __shfl(invl, g * 4 + reg);
                int t_loc = tg * 32 + h * 16 + g * 4 + reg;
                #pragma unroll
                for (int n = 0; n < 4; ++n) {
                    int c = n * 16 + i;
                    *(float*)(lds + swzO(c, t_loc * 4)) = oacc[h][n][reg] * inv_r;
                }
            }
        }
    }
    __syncthreads();
    #pragma unroll
    for (int it = 0; it < 4; ++it) {
        int idx = it * 512 + tid;
        int c   = idx >> 5;
        int seg = idx & 31;
        float4 u = *(const float4*)(lds + swzO(c, seg * 16));
        *(float4*)(out + (size_t)(bh * 64 + c) * T_LEN + t0 + seg * 4) = u;
    }
}

// ---------------- tiny correct fallback (ws too small; r3-verified) ---------
__global__ __launch_bounds__(256)
void simple_attn(const float* __restrict__ qkv, float* __restrict__ out) {
    const int wave = threadIdx.x >> 6;
    const int lane = threadIdx.x & 63;
    const int t  = blockIdx.x * 4 + wave;
    const int bh = blockIdx.y;
    const float* qp = qkv + (size_t)bh * 192 * T_LEN;
    const float* kp = qp + (size_t)64  * T_LEN;
    const float* vp = qp + (size_t)128 * T_LEN;
    const float qc = qp[(size_t)lane * T_LEN + t] * 0.125f;
    float m = -1e30f, l = 0.f, o = 0.f;
    for (int s = 0; s < T_LEN; ++s) {
        float prod = qc * kp[(size_t)lane * T_LEN + s];
        #pragma unroll
        for (int d = 1; d < 64; d <<= 1) prod += __shfl_xor(prod, d);
        const float nm   = fmaxf(m, prod);
        const float corr = __expf(m - nm);
        const float p    = __expf(prod - nm);
        l = l * corr + p;
        o = o * corr + p * vp[(size_t)lane * T_LEN + s];
        m = nm;
    }
    out[(size_t)(bh * 64 + lane) * T_LEN + t] = o / l;
}

extern "C" void kernel_launch(void* const* d_in, const int* in_sizes, int n_in,
                              void* d_out, int out_size, void* d_ws, size_t ws_size,
                              hipStream_t stream) {
    const float* qkv = (const float*)d_in[0];
    float* out = (float*)d_out;
    const size_t pan_bytes = (size_t)16 * 64 * 8192;   // 8.39 MB per panel set
    if (ws_size >= 2 * pan_bytes) {
        char* kpan = (char*)d_ws;
        char* vpan = kpan + pan_bytes;
        qkv_prepass<<<dim3(64, 16), 256, 0, stream>>>(qkv, kpan, vpan);
        qkv_attn_glds<<<dim3(512), 512, 0, stream>>>(qkv, out, kpan, vpan);
    } else {
        simple_attn<<<dim3(T_LEN / 4, 16), 256, 0, stream>>>(qkv, out);
    }
}